// Round 6
// baseline (233.121 us; speedup 1.0000x reference)
//
#include <hip/hip_runtime.h>

#define T_LEN 256
#define B_TOT 8192
#define RSCALE 3.2734375f
#define L2E    1.44269504f
#define LN2    0.693147180559945f

typedef __attribute__((ext_vector_type(2))) _Float16 h2;

__device__ __forceinline__ h2 pkrtz(float lo, float hi) {
    return __builtin_bit_cast(h2, __builtin_amdgcn_cvt_pkrtz(lo, hi));
}
__device__ __forceinline__ h2 h2cast(unsigned x) {
    return __builtin_bit_cast(h2, x);
}
__device__ __forceinline__ float ror8f(float x) {
    int xi = __float_as_int(x);
    int r = __builtin_amdgcn_update_dpp(xi, xi, 0x128, 0xF, 0xF, false); // ROW_ROR:8
    return __int_as_float(r);
}
__device__ __forceinline__ h2 ror1h(h2 x) {
    int xi = __builtin_bit_cast(int, x);
    int r = __builtin_amdgcn_update_dpp(xi, xi, 0x121, 0xF, 0xF, false); // ROW_ROR:1
    return __builtin_bit_cast(h2, r);
}
__device__ __forceinline__ h2 ror4h(h2 x) {
    int xi = __builtin_bit_cast(int, x);
    int r = __builtin_amdgcn_update_dpp(xi, xi, 0x124, 0xF, 0xF, false); // ROW_ROR:4
    return __builtin_bit_cast(h2, r);
}
// rotate f32 right by N within the 16-lane DPP row (VALU pipe, no LDS)
#define RORF(x, N) __int_as_float(__builtin_amdgcn_update_dpp( \
        __float_as_int(x), __float_as_int(x), 0x120 + (N), 0xF, 0xF, false))

// ---------------- pack: ctrl byte (tag | tidx<<4) + in-block gold trans/start reduce ----
__global__ __launch_bounds__(256) void pack_ctrl(
    const int* __restrict__ tags, const int* __restrict__ w2w,
    const int* __restrict__ ic,   const int* __restrict__ ds,
    const float* __restrict__ cw, const float* __restrict__ trans,
    const float* __restrict__ start,
    unsigned char* __restrict__ ctrl, float* __restrict__ goldsum)
{
    __shared__ float wsum[4];
    int idx = blockIdx.x * 256 + threadIdx.x;   // b*256 + t
    int b = blockIdx.x, t = threadIdx.x;
    int tag = tags[idx];
    unsigned char byte = (unsigned char)tag;
    float g;
    if (t == 0) {
        g = cw[tag] * start[tag];
    } else {
        int off = b * (T_LEN - 1) + (t - 1);
        int tidx = (w2w[off] == 1) ? 0 : ((ic[off] == 0) ? 1 : ((ds[off] == 0) ? 2 : 3));
        byte |= (unsigned char)(tidx << 4);
        g = cw[tag] * trans[tidx * 256 + tags[idx - 1] * 16 + tag];
    }
    ctrl[idx] = byte;

    float s = g;
#pragma unroll
    for (int m = 1; m < 64; m <<= 1) s += __shfl_xor(s, m, 64);
    if ((threadIdx.x & 63) == 0) wsum[threadIdx.x >> 6] = s;
    __syncthreads();
    if (threadIdx.x == 0) goldsum[b] = (wsum[0] + wsum[1]) + (wsum[2] + wsum[3]);
}

// ---------------- recurrence: 4 seqs/wave, 2048 waves, dot2-f16 matvec ----------------
// E-row select via LDS ring (depth-2 prefetch); ALL 16-lane reductions on the
// VALU pipe via DPP ROW_ROR (replaces serial ds_swizzle __shfl_xor chains);
// em refill via per-block base + immediate offsets.
__global__ __launch_bounds__(256, 2) void crf_rec(
    const float* __restrict__ em, const float* __restrict__ trans,
    const float* __restrict__ start, const float* __restrict__ cw,
    const unsigned char* __restrict__ ctrl,
    const float* __restrict__ goldsum, float* __restrict__ out)
{
    __shared__ float tl[1024];
    __shared__ __align__(16) unsigned char Dl[3072];  // [c]*768 + [j]*48 + [r]*4, h2 entries

    for (int i = threadIdx.x; i < 1024; i += 256) tl[i] = trans[i];
    __syncthreads();

    const int j = threadIdx.x & 15;

    // DPP rotation-direction probe (proven in R1/R2); delta is lane-uniform
    int pr    = __builtin_amdgcn_update_dpp(j, j, 0x121, 0xF, 0xF, false);
    int delta = (pr - j) & 15;

    // Build Dl: 256 threads x 2 entries = 4*16*8 h2
    {
        int c  = threadIdx.x >> 6;
        int jj = (threadIdx.x >> 2) & 15;
        int r0 = (threadIdx.x & 3) * 2;
#pragma unroll
        for (int q = 0; q < 2; ++q) {
            int r = r0 + q;
            float lo = __expf(tl[c * 256 + ((jj + r * delta) & 15) * 16 + jj]);
            float hi = __expf(tl[c * 256 + ((jj + (r + 8) * delta) & 15) * 16 + jj]);
            *(h2*)&Dl[c * 768 + jj * 48 + r * 4] = pkrtz(lo, hi);
        }
    }
    __syncthreads();

    const int seq = (blockIdx.x * 256 + threadIdx.x) >> 4;
    const float cw_j = cw[j];
    const float st_j = start[j];
    const float* ep  = em + (size_t)seq * 4096 + j;
    const uint4* cp  = (const uint4*)(ctrl + (size_t)seq * 256);
    const unsigned char* Dbase = &Dl[j * 48];

    // 16-deep emission ring (1 f32/lane/step)
    float emr[16];
#pragma unroll
    for (int k = 0; k < 16; ++k) emr[k] = ep[k * 16];
    uint4 cq = cp[0], cqn = cp[1];

    // 4-slot E-row ring (compile-time indexed only), prefetch distance 2
    uint4 qa[4], qb[4];

    float u, ge, logC = 5.545177444479562f;   // 8*ln2: u0 pre-scaled 2^-8
    {
        int tag0 = (int)(cq.x & 15u);
        u  = __expf(st_j + emr[0]) * 0.00390625f;
        ge = (j == tag0) ? cw_j * emr[0] : 0.0f;
        emr[0] = ep[256];                      // refill slot 0 with t=16
        // preload E-rows for steps k=1 (slot 1) and k=2 (slot 2)
        unsigned c1 = (cq.x >> 12) & 3u;
        const uint4* p1 = (const uint4*)(Dbase + c1 * 768);
        qa[1] = p1[0]; qb[1] = p1[1];
        unsigned c2 = (cq.x >> 20) & 3u;
        const uint4* p2 = (const uint4*)(Dbase + c2 * 768);
        qa[2] = p2[0]; qb[2] = p2[1];
    }

    // rb = refill base for current block: refill target for step k is rb[k*16]
    auto STEP = [&](int k, const float* rb, bool pf) __attribute__((always_inline)) {
        // ---- prefetch E-row two steps ahead into slot (k+2)&3 ----
        {
            int kk = k + 2;                                // window pos 2..17
            const uint4& qn = (kk < 16) ? cq : cqn;
            int km = kk & 15;
            unsigned dwn = (km < 4) ? qn.x : (km < 8) ? qn.y : (km < 12) ? qn.z : qn.w;
            unsigned cn = (dwn >> (8 * (km & 3) + 4)) & 3u;
            const uint4* pn = (const uint4*)(Dbase + cn * 768);
            qa[(k + 2) & 3] = pn[0];
            qb[(k + 2) & 3] = pn[1];
        }
        unsigned dw = (k < 4) ? cq.x : (k < 8) ? cq.y : (k < 12) ? cq.z : cq.w;
        int sh = 8 * (k & 3);
        int tag = (int)((dw >> sh) & 15u);

        // pair (u_j, u_{j+8d}) in f16; two serial ror1 chains (rot 0..3 / 4..7)
        uint4 A = qa[k & 3], B = qb[k & 3];
        float uh = ror8f(u);
        h2 P = pkrtz(u, uh);
        h2 Q = ror4h(P);
        float s0 = __builtin_amdgcn_fdot2(P, h2cast(A.x), 0.0f, false);
        float s1 = __builtin_amdgcn_fdot2(Q, h2cast(B.x), 0.0f, false);
        P = ror1h(P); Q = ror1h(Q);
        s0 = __builtin_amdgcn_fdot2(P, h2cast(A.y), s0, false);
        s1 = __builtin_amdgcn_fdot2(Q, h2cast(B.y), s1, false);
        P = ror1h(P); Q = ror1h(Q);
        s0 = __builtin_amdgcn_fdot2(P, h2cast(A.z), s0, false);
        s1 = __builtin_amdgcn_fdot2(Q, h2cast(B.z), s1, false);
        P = ror1h(P); Q = ror1h(Q);
        s0 = __builtin_amdgcn_fdot2(P, h2cast(A.w), s0, false);
        s1 = __builtin_amdgcn_fdot2(Q, h2cast(B.w), s1, false);
        float s = s0 + s1;
        float exf = __builtin_exp2f(fmaf(emr[k], L2E, -RSCALE * L2E));
        if (j == tag) ge = fmaf(cw_j, emr[k], ge);   // gold em-term
        u = s * exf;
        if (pf) emr[k] = rb[k * 16];                 // refill 16 steps ahead (imm offset)
        if ((k & 7) == 7) {                          // exact pow2 renorm, -4 bias
            // 16-lane max via DPP rotations (VALU pipe, no ds_swizzle)
            float mx = u;
            mx = fmaxf(mx, RORF(mx, 1));
            mx = fmaxf(mx, RORF(mx, 2));
            mx = fmaxf(mx, RORF(mx, 4));
            mx = fmaxf(mx, RORF(mx, 8));
            // frexp/ldexp via exponent-field bit ops (mx > 0, normal); proven R3/R4
            int eb = (__float_as_int(mx) >> 23) & 255;   // e2 = eb - 126
            u *= __int_as_float((249 - eb) << 23);        // u * 2^(-e2-4)
            logC += (float)(eb - 122) * LN2;              // (e2+4)*ln2
        }
    };

    // block 0: t=1..15 (refill base = ep + 256)
    {
        const float* rb = ep + 256;
#pragma unroll
        for (int k = 1; k < 16; ++k) STEP(k, rb, true);
    }
    // blocks 1..14 with prefetch
    for (int blk = 1; blk < 15; ++blk) {
        cq = cqn;
        cqn = cp[blk + 1];
        const float* rb = ep + (size_t)(blk + 1) * 256;
#pragma unroll
        for (int k = 0; k < 16; ++k) STEP(k, rb, true);
    }
    // peeled last block: t=240..255, no em prefetch (E-prefetch reads stale cqn: harmless)
    cq = cqn;
#pragma unroll
    for (int k = 0; k < 16; ++k) STEP(k, ep, false);

    // group reductions via DPP rotations (full 16-lane ring)
    float su = u, gs = ge;
    su += RORF(su, 1); gs += RORF(gs, 1);
    su += RORF(su, 2); gs += RORF(gs, 2);
    su += RORF(su, 4); gs += RORF(gs, 4);
    su += RORF(su, 8); gs += RORF(gs, 8);
    if (j == 0) {
        out[seq]         = gs + goldsum[seq];
        out[B_TOT + seq] = logf(su) + 255.0f * RSCALE + logC;
    }
}

extern "C" void kernel_launch(void* const* d_in, const int* in_sizes, int n_in,
                              void* d_out, int out_size, void* d_ws, size_t ws_size,
                              hipStream_t stream) {
    const float* emissions     = (const float*)d_in[0];
    const int*   tags          = (const int*)  d_in[1];
    const int*   who2who       = (const int*)  d_in[2];
    const int*   init_count    = (const int*)  d_in[3];
    const int*   distance      = (const int*)  d_in[4];
    const float* class_weights = (const float*)d_in[5];
    const float* trans_stack   = (const float*)d_in[6];
    const float* start_scores  = (const float*)d_in[7];
    float* out = (float*)d_out;

    char* ws = (char*)d_ws;
    unsigned char* ctrl    = (unsigned char*)ws;         // 2 MB
    float*         goldsum = (float*)(ws + (2 << 20));   // 32 KB

    hipLaunchKernelGGL(pack_ctrl, dim3(B_TOT), dim3(256), 0, stream,
                       tags, who2who, init_count, distance,
                       class_weights, trans_stack, start_scores, ctrl, goldsum);

    hipLaunchKernelGGL(crf_rec, dim3(B_TOT * 16 / 256), dim3(256), 0, stream,
                       emissions, trans_stack, start_scores, class_weights,
                       ctrl, goldsum, out);
}